// Round 13
// baseline (215.047 us; speedup 1.0000x reference)
//
#include <hip/hip_runtime.h>
#include <math.h>

#define B_DIM 2
#define S_DIM 2048
#define D_DIM 1024
#define H_NUM 16
#define DH    64
#define M_DIM (B_DIM * S_DIM) /* 4096 */

typedef __attribute__((ext_vector_type(8))) short short8;
typedef __attribute__((ext_vector_type(4))) short short4v;
typedef __attribute__((ext_vector_type(4))) float float4v;
typedef __attribute__((ext_vector_type(4))) unsigned short ushort4v;
typedef unsigned short ushort;

static __device__ __forceinline__ ushort f2bf(float f) {
    unsigned u = __float_as_uint(f);
    u += 0x7fffu + ((u >> 16) & 1u);
    return (ushort)(u >> 16);
}

static __device__ __forceinline__ float fexp2(float x) {
#if __has_builtin(__builtin_amdgcn_exp2f)
    return __builtin_amdgcn_exp2f(x);
#else
    return exp2f(x);
#endif
}

// 2 f32 -> 2 bf16 in one u32, lo half = first arg (proven: rounds 3/4
// bit-identical).
static __device__ __forceinline__ unsigned cvtpk_bf16(float lo, float hi) {
    unsigned r;
    asm("v_cvt_pk_bf16_f32 %0, %1, %2" : "=v"(r) : "v"(lo), "v"(hi));
    return r;
}

static __device__ __forceinline__ void gload_lds16(const void* g, void* l) {
    __builtin_amdgcn_global_load_lds(
        (const __attribute__((address_space(1))) void*)g,
        (__attribute__((address_space(3))) void*)l, 16, 0, 0);
}

// ---------------------------------------------------------------------------
// Fused fp32 -> bf16 cast of ALL five tensors in one launch.
// dst layout (contiguous in ws): xh[4M] | wq[1M] | wk[1M] | wv[1M] | wo[1M]
// ---------------------------------------------------------------------------
__global__ __launch_bounds__(256)
void cast_all(const float* __restrict__ x,  const float* __restrict__ wq,
              const float* __restrict__ wk, const float* __restrict__ wv,
              const float* __restrict__ wo, ushort* __restrict__ dst)
{
    const int i = blockIdx.x * 256 + threadIdx.x;   // 0 .. 2M-1 (float4 units)
    const float4* s;
    int off;
    if      (i < 1048576) { s = (const float4*)x;  off = 0;       }
    else if (i < 1310720) { s = (const float4*)wq; off = 1048576; }
    else if (i < 1572864) { s = (const float4*)wk; off = 1310720; }
    else if (i < 1835008) { s = (const float4*)wv; off = 1572864; }
    else                  { s = (const float4*)wo; off = 1835008; }
    const float4 v = s[i - off];
    ushort4v o;
    o[0] = f2bf(v.x); o[1] = f2bf(v.y); o[2] = f2bf(v.z); o[3] = f2bf(v.w);
    ((ushort4v*)dst)[i] = o;
}

// ---------------------------------------------------------------------------
// QKV GEMM, BK=64, double-buffered single-barrier K-loop (R12, verified).
// Granule-XOR LDS swizzle; XCD-aware bijective block swizzle (768=8*96).
// A:[4096,1024] bf16, B:[3072,1024] bf16 row-major.
// n>>10 selects dst: 0->Qh [B,H,S,Dh] (PRE-SCALED by 0.125*log2e),
// 1->Kh [B,H,S,Dh], 2->Vt [B,H,Dh,S]; all bf16.
// ---------------------------------------------------------------------------
__global__ __launch_bounds__(256)
void gemm_bf16(const ushort* __restrict__ A, const ushort* __restrict__ B,
               ushort* __restrict__ Qh, ushort* __restrict__ Kh,
               ushort* __restrict__ Vt)
{
    __shared__ ushort Asm[2][128 * 64];   // [buf][row][k 64], granule-swizzled
    __shared__ ushort Bsm[2][128 * 64];

    const int K = 1024;
    const int NT = 16;                                 // K-tiles
    const int lin = blockIdx.y * 24 + blockIdx.x;      // hardware linear id
    const int swz = (lin & 7) * 96 + (lin >> 3);       // bijective (768=8*96)
    const int n0 = (swz % 24) * 128;
    const int m0 = (swz / 24) * 128;
    const int t    = threadIdx.x;
    const int w    = t >> 6;
    const int lane = t & 63;
    const int n    = lane & 15;
    const int quad = lane >> 4;
    const int wm = w >> 1, wn = w & 1;

    const int l8 = lane >> 3;
    const int sg = (lane & 7) ^ l8;

    const int fswz[2] = { ((0 * 4 + quad) ^ (n & 7)) * 8,
                          ((1 * 4 + quad) ^ (n & 7)) * 8 };

    float4v acc[4][4];
#pragma unroll
    for (int mt = 0; mt < 4; ++mt)
#pragma unroll
        for (int nt = 0; nt < 4; ++nt) acc[mt][nt] = (float4v){0.f, 0.f, 0.f, 0.f};

    // prologue: stage tile 0 into buffer 0
#pragma unroll
    for (int i = 0; i < 4; ++i) {
        gload_lds16(&A[(size_t)(m0 + w * 32 + i * 8 + l8) * K + sg * 8],
                    &Asm[0][(w * 32 + i * 8) * 64]);
        gload_lds16(&B[(size_t)(n0 + w * 32 + i * 8 + l8) * K + sg * 8],
                    &Bsm[0][(w * 32 + i * 8) * 64]);
    }

    for (int kt6 = 0; kt6 < NT; ++kt6) {
        __syncthreads();   // stage(kt6) complete; buf cur^1 free for overwrite
        const int cur = kt6 & 1;
        if (kt6 + 1 < NT) {
            const int kt1 = (kt6 + 1) * 64;
            const int nxt = cur ^ 1;
#pragma unroll
            for (int i = 0; i < 4; ++i) {
                gload_lds16(&A[(size_t)(m0 + w * 32 + i * 8 + l8) * K + kt1 + sg * 8],
                            &Asm[nxt][(w * 32 + i * 8) * 64]);
                gload_lds16(&B[(size_t)(n0 + w * 32 + i * 8 + l8) * K + kt1 + sg * 8],
                            &Bsm[nxt][(w * 32 + i * 8) * 64]);
            }
        }

        short8 af[4][2], bfr[4][2];
#pragma unroll
        for (int mt = 0; mt < 4; ++mt)
#pragma unroll
            for (int kk = 0; kk < 2; ++kk)
                af[mt][kk] = *(const short8*)&Asm[cur][(wm * 64 + mt * 16 + n) * 64 + fswz[kk]];
#pragma unroll
        for (int nt = 0; nt < 4; ++nt)
#pragma unroll
            for (int kk = 0; kk < 2; ++kk)
                bfr[nt][kk] = *(const short8*)&Bsm[cur][(wn * 64 + nt * 16 + n) * 64 + fswz[kk]];

        __builtin_amdgcn_s_setprio(1);
#pragma unroll
        for (int mt = 0; mt < 4; ++mt)
#pragma unroll
            for (int nt = 0; nt < 4; ++nt) {
                acc[mt][nt] = __builtin_amdgcn_mfma_f32_16x16x32_bf16(
                    af[mt][0], bfr[nt][0], acc[mt][nt], 0, 0, 0);
                acc[mt][nt] = __builtin_amdgcn_mfma_f32_16x16x32_bf16(
                    af[mt][1], bfr[nt][1], acc[mt][nt], 0, 0, 0);
            }
        __builtin_amdgcn_s_setprio(0);
    }

    const int wid = n0 >> 10;           // 0=Q 1=K 2=V (constant per block)
    ushort* dstQK = (wid == 0) ? Qh : Kh;
    const float qs = (wid == 0) ? 0.1803368801f : 1.0f;  // 0.125*log2(e)
#pragma unroll
    for (int mt = 0; mt < 4; ++mt) {
        const int m = m0 + wm * 64 + mt * 16 + quad * 4;   // +r
        const int b = m >> 11, s = m & (S_DIM - 1);
#pragma unroll
        for (int nt = 0; nt < 4; ++nt) {
            const int ng = (n0 & 1023) + wn * 64 + nt * 16 + n;
            const int h = ng >> 6, d = ng & 63;
            const int bh = b * H_NUM + h;
            if (wid < 2) {
#pragma unroll
                for (int r = 0; r < 4; ++r)
                    dstQK[(((size_t)bh * S_DIM + s + r) << 6) + d] =
                        f2bf(acc[mt][nt][r] * qs);
            } else {
                ushort4v p;
#pragma unroll
                for (int r = 0; r < 4; ++r) p[r] = f2bf(acc[mt][nt][r]);
                *(ushort4v*)&Vt[(((size_t)bh * DH + d) << 11) + s] = p;
            }
        }
    }
}

// ---------------------------------------------------------------------------
// Out-projection GEMM, 128x64 tile, BK=64, double-buffered (R12, verified).
// Grid (16,32)=512 = 2 blocks/CU; XCD swizzle bijective (512=8*64).
// A=Yh [4096,1024], B=Woh [1024,1024] bf16 row-major.
// fp32 out[m*1024+n] = acc + bias[n].
// ---------------------------------------------------------------------------
__global__ __launch_bounds__(256)
void gemm_out(const ushort* __restrict__ A, const ushort* __restrict__ B,
              float* __restrict__ Of, const float* __restrict__ bias)
{
    __shared__ ushort Asm[2][128 * 64];
    __shared__ ushort Bsm[2][64 * 64];

    const int K = 1024;
    const int NT = 16;
    const int lin = blockIdx.y * 16 + blockIdx.x;
    const int swz = (lin & 7) * 64 + (lin >> 3);       // bijective (512=8*64)
    const int n0 = (swz % 16) * 64;
    const int m0 = (swz / 16) * 128;
    const int t    = threadIdx.x;
    const int w    = t >> 6;
    const int lane = t & 63;
    const int n    = lane & 15;
    const int quad = lane >> 4;
    const int wm = w >> 1, wn = w & 1;

    const int l8 = lane >> 3;
    const int sg = (lane & 7) ^ l8;
    const int fswz[2] = { ((0 * 4 + quad) ^ (n & 7)) * 8,
                          ((1 * 4 + quad) ^ (n & 7)) * 8 };

    float4v acc[4][2];
#pragma unroll
    for (int mt = 0; mt < 4; ++mt)
#pragma unroll
        for (int nt = 0; nt < 2; ++nt) acc[mt][nt] = (float4v){0.f, 0.f, 0.f, 0.f};

    // prologue: stage tile 0 into buffer 0
#pragma unroll
    for (int i = 0; i < 4; ++i)
        gload_lds16(&A[(size_t)(m0 + w * 32 + i * 8 + l8) * K + sg * 8],
                    &Asm[0][(w * 32 + i * 8) * 64]);
#pragma unroll
    for (int i = 0; i < 2; ++i)
        gload_lds16(&B[(size_t)(n0 + w * 16 + i * 8 + l8) * K + sg * 8],
                    &Bsm[0][(w * 16 + i * 8) * 64]);

    for (int kt6 = 0; kt6 < NT; ++kt6) {
        __syncthreads();
        const int cur = kt6 & 1;
        if (kt6 + 1 < NT) {
            const int kt1 = (kt6 + 1) * 64;
            const int nxt = cur ^ 1;
#pragma unroll
            for (int i = 0; i < 4; ++i)
                gload_lds16(&A[(size_t)(m0 + w * 32 + i * 8 + l8) * K + kt1 + sg * 8],
                            &Asm[nxt][(w * 32 + i * 8) * 64]);
#pragma unroll
            for (int i = 0; i < 2; ++i)
                gload_lds16(&B[(size_t)(n0 + w * 16 + i * 8 + l8) * K + kt1 + sg * 8],
                            &Bsm[nxt][(w * 16 + i * 8) * 64]);
        }

        short8 af[4][2], bfr[2][2];
#pragma unroll
        for (int mt = 0; mt < 4; ++mt)
#pragma unroll
            for (int kk = 0; kk < 2; ++kk)
                af[mt][kk] = *(const short8*)&Asm[cur][(wm * 64 + mt * 16 + n) * 64 + fswz[kk]];
#pragma unroll
        for (int nt = 0; nt < 2; ++nt)
#pragma unroll
            for (int kk = 0; kk < 2; ++kk)
                bfr[nt][kk] = *(const short8*)&Bsm[cur][(wn * 32 + nt * 16 + n) * 64 + fswz[kk]];

        __builtin_amdgcn_s_setprio(1);
#pragma unroll
        for (int mt = 0; mt < 4; ++mt)
#pragma unroll
            for (int nt = 0; nt < 2; ++nt) {
                acc[mt][nt] = __builtin_amdgcn_mfma_f32_16x16x32_bf16(
                    af[mt][0], bfr[nt][0], acc[mt][nt], 0, 0, 0);
                acc[mt][nt] = __builtin_amdgcn_mfma_f32_16x16x32_bf16(
                    af[mt][1], bfr[nt][1], acc[mt][nt], 0, 0, 0);
            }
        __builtin_amdgcn_s_setprio(0);
    }

#pragma unroll
    for (int mt = 0; mt < 4; ++mt) {
        const int m = m0 + wm * 64 + mt * 16 + quad * 4;
#pragma unroll
        for (int nt = 0; nt < 2; ++nt) {
            const int ng = n0 + wn * 32 + nt * 16 + n;
            const float bv = bias[ng];
#pragma unroll
            for (int r = 0; r < 4; ++r)
                Of[(size_t)(m + r) * D_DIM + ng] = acc[mt][nt][r] + bv;
        }
    }
}

// ---------------------------------------------------------------------------
// MFMA flash attention, R7/R11 structure + SPLIT-KV for occupancy.
// R12 counters: grid 512 = 2 blocks/CU = 2 waves/SIMD was the binding limit
// (VGPR and LDS allow more); VALUBusy 48% latency-bound. Split-KV keeps the
// proven 32 q-rows/wave geometry and halves each block's KV range:
// grid (512, 2) = 1024 blocks = 4 blocks/CU = 16 waves/CU. Per-CU VALU/
// MFMA/LDS work invariant (each half stages only its own K/V tiles).
// partial=1: write unnormalized O (f32) + per-row {m, l} to workspace;
// attn_merge combines (exact: O_s, l_s consistent with m_s).
// partial=0 (fallback, ws too small): identical to R12 single-pass.
// ---------------------------------------------------------------------------
__global__ __launch_bounds__(256)
void attn_mfma(const ushort* __restrict__ Qh, const ushort* __restrict__ Kh,
               const ushort* __restrict__ Vt, ushort* __restrict__ Yh,
               float* __restrict__ Op, float* __restrict__ Lm,
               int nkb, int partial)
{
    __shared__ ushort Ksm[2][64 * 64];   // [buf][key 64][d 64] granule-swizzled
    __shared__ ushort Vsm[2][64 * 64];   // [buf][d 64][key 64] granule-swizzled

    const int w    = threadIdx.x >> 6;
    const int lane = threadIdx.x & 63;
    const int n    = lane & 15;
    const int quad = lane >> 4;

    const int wave_id = blockIdx.x * 4 + w;
    const int bh    = wave_id >> 6;          // all 4 waves of a block: same bh
    const int qbase = (wave_id & 63) * 32;
    const int b     = bh >> 4;
    const int h     = bh & (H_NUM - 1);
    const int s     = blockIdx.y;            // KV-split index (0 when full)
    const int kb0   = s * nkb, kb1 = kb0 + nkb;

    const ushort* Qb = Qh + (((size_t)bh * S_DIM) << 6);
    const ushort* Kb = Kh + (((size_t)bh * S_DIM) << 6);
    const ushort* Vb = Vt + (((size_t)bh * DH) << 11);

    const int l8 = lane >> 3;
    const int sg = (lane & 7) ^ l8;

    short8 qa[2][2];   // B-frag: lane holds Q[q = mt*16+n][d = kc*32+quad*8 ..]
#pragma unroll
    for (int mt = 0; mt < 2; ++mt)
#pragma unroll
        for (int kc = 0; kc < 2; ++kc)
            qa[mt][kc] = *(const short8*)&Qb[((size_t)(qbase + mt * 16 + n) << 6) + kc * 32 + quad * 8];

    float4v O[2][4];           // O[mt][nt][r]: q = mt*16+quad*4+r, d = nt*16+n
    float   mrow[2], lrow[2];  // per-lane: q = mt*16 + n (uniform over quads)
#pragma unroll
    for (int mt = 0; mt < 2; ++mt) {
#pragma unroll
        for (int nt = 0; nt < 4; ++nt) O[mt][nt] = (float4v){0.f, 0.f, 0.f, 0.f};
        mrow[mt] = -1e30f; lrow[mt] = 0.f;
    }

    const int fswz[2] = { ((0 * 4 + quad) ^ (n & 7)) * 8,
                          ((1 * 4 + quad) ^ (n & 7)) * 8 };
    const int h4 = (quad & 1) * 4;
    const int q2 = quad >> 1;
    int vswz[2][2];
#pragma unroll
    for (int kc = 0; kc < 2; ++kc)
#pragma unroll
        for (int cc = 0; cc < 2; ++cc)
            vswz[kc][cc] = (((4 * kc + 2 * cc + q2) ^ (n & 7)) << 3) + h4;

    // prologue: stage tile kb0 into buffer 0
    const int keyp = kb0 * 64;
#pragma unroll
    for (int i = 0; i < 2; ++i) {
        gload_lds16(&Kb[(size_t)(keyp + w * 16 + i * 8 + l8) * 64 + sg * 8],
                    &Ksm[0][(w * 16 + i * 8) * 64]);
        gload_lds16(&Vb[(size_t)(w * 16 + i * 8 + l8) * 2048 + keyp + sg * 8],
                    &Vsm[0][(w * 16 + i * 8) * 64]);
    }

    for (int kb = kb0; kb < kb1; ++kb) {
        __syncthreads();   // stage(kb) complete; buf cur^1 free for overwrite
        const int cur = (kb - kb0) & 1;
        if (kb + 1 < kb1) {
            const int key1 = (kb + 1) * 64;
            const int nxt  = cur ^ 1;
#pragma unroll
            for (int i = 0; i < 2; ++i) {
                gload_lds16(&Kb[(size_t)(key1 + w * 16 + i * 8 + l8) * 64 + sg * 8],
                            &Ksm[nxt][(w * 16 + i * 8) * 64]);
                gload_lds16(&Vb[(size_t)(w * 16 + i * 8 + l8) * 2048 + key1 + sg * 8],
                            &Vsm[nxt][(w * 16 + i * 8) * 64]);
            }
        }

        // A-frag: lane holds K[key = ct*16+n][d = kc*32+quad*8 ..]
        short8 kf[4][2];
#pragma unroll
        for (int ct = 0; ct < 4; ++ct)
#pragma unroll
            for (int kc = 0; kc < 2; ++kc)
                kf[ct][kc] = *(const short8*)&Ksm[cur][(ct * 16 + n) * 64 + fswz[kc]];

        // S^T[key][q]: s[mt][ct][r] = S[q = mt*16+n][key = ct*16+quad*4+r]
        float4v sc[2][4];
        __builtin_amdgcn_s_setprio(1);
#pragma unroll
        for (int mt = 0; mt < 2; ++mt)
#pragma unroll
            for (int ct = 0; ct < 4; ++ct) {
                float4v a = (float4v){0.f, 0.f, 0.f, 0.f};
                a = __builtin_amdgcn_mfma_f32_16x16x32_bf16(kf[ct][0], qa[mt][0], a, 0, 0, 0);
                a = __builtin_amdgcn_mfma_f32_16x16x32_bf16(kf[ct][1], qa[mt][1], a, 0, 0, 0);
                sc[mt][ct] = a;
            }
        __builtin_amdgcn_s_setprio(0);

        // B-frag under remap: slot q*8+e holds V[key = 32kc+16(e>>2)+4q+(e&3)]
        short8 vf[4][2];
#pragma unroll
        for (int nt = 0; nt < 4; ++nt) {
            const int rb = (nt * 16 + n) * 64;
#pragma unroll
            for (int kc = 0; kc < 2; ++kc) {
                const short4v g0 = *(const short4v*)&Vsm[cur][rb + vswz[kc][0]];
                const short4v g1 = *(const short4v*)&Vsm[cur][rb + vswz[kc][1]];
                vf[nt][kc] = __builtin_shufflevector(g0, g1, 0, 1, 2, 3, 4, 5, 6, 7);
            }
        }

#pragma unroll
        for (int mt = 0; mt < 2; ++mt) {
            // tile max for q = mt*16+n (my 16 keys, then across quads)
            float lm = sc[mt][0][0];
#pragma unroll
            for (int ct = 0; ct < 4; ++ct)
#pragma unroll
                for (int r = 0; r < 4; ++r)
                    lm = fmaxf(lm, sc[mt][ct][r]);
            lm = fmaxf(lm, __shfl_xor(lm, 16, 64));
            lm = fmaxf(lm, __shfl_xor(lm, 32, 64));

            const bool ev = lm > mrow[mt] + 8.0f;   // defer-max threshold
            if (__any(ev)) {
                const float mnew  = ev ? lm : mrow[mt];
                const float alpha = fexp2(mrow[mt] - mnew);  // 1.0 when !ev
                mrow[mt] = mnew;
                lrow[mt] *= alpha;
                const int ai = __float_as_int(alpha);
                float av[4];
#pragma unroll
                for (int r = 0; r < 4; ++r)
                    av[r] = __int_as_float(
                        __builtin_amdgcn_ds_bpermute(4 * (quad * 4 + r), ai));
#pragma unroll
                for (int nt = 0; nt < 4; ++nt)
#pragma unroll
                    for (int r = 0; r < 4; ++r) O[mt][nt][r] *= av[r];
            }

            // P = 2^(s - m); l as local partial (reduced once at the end)
            float pv[4][4];
            float lsum = 0.f;
#pragma unroll
            for (int ct = 0; ct < 4; ++ct)
#pragma unroll
                for (int r = 0; r < 4; ++r) {
                    const float p = fexp2(sc[mt][ct][r] - mrow[mt]);
                    pv[ct][r] = p;
                    lsum += p;
                }
            lrow[mt] += lsum;

            // PV A-frag is PURELY LOCAL under the remap:
            // element e of pk[kc] = pv[2kc + (e>>2)][e&3]; cvt_pk = 1 instr.
            union { unsigned u[4]; short8 s8; } pk[2];
#pragma unroll
            for (int kc = 0; kc < 2; ++kc) {
                pk[kc].u[0] = cvtpk_bf16(pv[2 * kc][0],     pv[2 * kc][1]);
                pk[kc].u[1] = cvtpk_bf16(pv[2 * kc][2],     pv[2 * kc][3]);
                pk[kc].u[2] = cvtpk_bf16(pv[2 * kc + 1][0], pv[2 * kc + 1][1]);
                pk[kc].u[3] = cvtpk_bf16(pv[2 * kc + 1][2], pv[2 * kc + 1][3]);
            }

            __builtin_amdgcn_s_setprio(1);
#pragma unroll
            for (int nt = 0; nt < 4; ++nt) {
                O[mt][nt] = __builtin_amdgcn_mfma_f32_16x16x32_bf16(pk[0].s8, vf[nt][0], O[mt][nt], 0, 0, 0);
                O[mt][nt] = __builtin_amdgcn_mfma_f32_16x16x32_bf16(pk[1].s8, vf[nt][1], O[mt][nt], 0, 0, 0);
            }
            __builtin_amdgcn_s_setprio(0);
        }
    }

    if (!partial) {
#pragma unroll
        for (int mt = 0; mt < 2; ++mt) {
            float ls = lrow[mt];
            ls += __shfl_xor(ls, 16, 64);
            ls += __shfl_xor(ls, 32, 64);
            const float linv = 1.f / ls;            // at lane: q = mt*16 + n
            const int  li = __float_as_int(linv);
            float lv[4];
#pragma unroll
            for (int r = 0; r < 4; ++r)
                lv[r] = __int_as_float(
                    __builtin_amdgcn_ds_bpermute(4 * (quad * 4 + r), li));
#pragma unroll
            for (int nt = 0; nt < 4; ++nt)
#pragma unroll
                for (int r = 0; r < 4; ++r) {
                    const int q = qbase + mt * 16 + quad * 4 + r;
                    Yh[((size_t)(b * S_DIM + q) << 10) + h * DH + nt * 16 + n] =
                        f2bf(O[mt][nt][r] * lv[r]);
                }
        }
    } else {
        float* Ops = Op + (size_t)s * ((size_t)M_DIM * 1024);   // 4M f32 per s
        float* Lms = Lm + (size_t)s * (32 * S_DIM * 2);
#pragma unroll
        for (int mt = 0; mt < 2; ++mt) {
            float ls = lrow[mt];
            ls += __shfl_xor(ls, 16, 64);
            ls += __shfl_xor(ls, 32, 64);
            if (quad == 0) {        // lanes 0..15 own q = qbase+mt*16+n
                const int q = qbase + mt * 16 + n;
                Lms[((size_t)bh * S_DIM + q) * 2 + 0] = mrow[mt];
                Lms[((size_t)bh * S_DIM + q) * 2 + 1] = ls;
            }
#pragma unroll
            for (int r = 0; r < 4; ++r) {
                const int q = qbase + mt * 16 + quad * 4 + r;
                const size_t base = ((size_t)bh * S_DIM + q) * DH;
#pragma unroll
                for (int nt = 0; nt < 4; ++nt)
                    Ops[base + nt * 16 + n] = O[mt][nt][r];
            }
        }
    }
}

// ---------------------------------------------------------------------------
// Split-KV merge: O = (O0*a0 + O1*a1) / (l0*a0 + l1*a1), a_s = 2^(m_s - m*).
// Exact (each half's O_s, l_s consistent with its own m_s). float4 per thread.
// ---------------------------------------------------------------------------
__global__ __launch_bounds__(256)
void attn_merge(const float* __restrict__ Op, const float* __restrict__ Lm,
                ushort* __restrict__ Yh)
{
    const int idx = blockIdx.x * 256 + threadIdx.x;    // 0 .. 1M-1
    const int d4 = idx & 15;
    const int q  = (idx >> 4) & (S_DIM - 1);
    const int bh = idx >> 15;
    const size_t po = ((size_t)bh * S_DIM + q) * DH + d4 * 4;
    const float4 o0 = *(const float4*)(Op + po);
    const float4 o1 = *(const float4*)(Op + (size_t)M_DIM * 1024 + po);
    const size_t li = ((size_t)bh * S_DIM + q) * 2;
    const float m0 = Lm[li],              l0 = Lm[li + 1];
    const float m1 = Lm[32 * S_DIM * 2 + li], l1 = Lm[32 * S_DIM * 2 + li + 1];
    const float mm = fmaxf(m0, m1);
    const float a0 = fexp2(m0 - mm), a1 = fexp2(m1 - mm);
    const float linv = 1.f / (l0 * a0 + l1 * a1);
    ushort4v y;
    y[0] = f2bf((o0.x * a0 + o1.x * a1) * linv);
    y[1] = f2bf((o0.y * a0 + o1.y * a1) * linv);
    y[2] = f2bf((o0.z * a0 + o1.z * a1) * linv);
    y[3] = f2bf((o0.w * a0 + o1.w * a1) * linv);
    const int b = bh >> 4, h = bh & (H_NUM - 1);
    *(ushort4v*)&Yh[((size_t)(b * S_DIM + q) << 10) + h * DH + d4 * 4] = y;
}

// ---------------------------------------------------------------------------
extern "C" void kernel_launch(void* const* d_in, const int* in_sizes, int n_in,
                              void* d_out, int out_size, void* d_ws, size_t ws_size,
                              hipStream_t stream)
{
    const float* x  = (const float*)d_in[0];
    const float* wq = (const float*)d_in[1];
    const float* wk = (const float*)d_in[2];
    const float* wv = (const float*)d_in[3];
    const float* wo = (const float*)d_in[4];
    const float* bo = (const float*)d_in[5];
    float* out = (float*)d_out;

    const size_t MD = (size_t)M_DIM * D_DIM;      // 4M elements
    const size_t WD = (size_t)D_DIM * D_DIM;      // 1M elements
    ushort* xh  = (ushort*)d_ws;      // 8 MB  [M,K] bf16
    ushort* Wh  = xh + MD;            // 6 MB  [3072,1024] bf16 (wq|wk|wv)
    ushort* Woh = Wh + 3 * WD;        // 2 MB  [1024,1024] bf16
    ushort* Qh  = Woh + WD;           // 8 MB  [B,H,S,Dh] bf16 (pre-scaled)
    ushort* Kh  = Qh + MD;            // 8 MB  [B,H,S,Dh] bf16
    ushort* Vt  = Kh + MD;            // 8 MB  [B,H,Dh,S] bf16
    ushort* Yh  = Vt + MD;            // 8 MB  [M,D] bf16
    float*  Op  = (float*)(Yh + MD);  // 32 MB [2][4M] f32 (split-KV partials)
    float*  Lm  = Op + 2 * MD;        // 1 MB  [2][32*2048*2] f32
    if (ws_size < 48u * 1024u * 1024u) return;
    const bool split = ws_size >= 81u * 1024u * 1024u;

    dim3 blk(256);
    cast_all<<<dim3(8192), blk, 0, stream>>>(x, wq, wk, wv, wo, xh);

    gemm_bf16<<<dim3(24, 32), blk, 0, stream>>>(xh, Wh, Qh, Kh, Vt);
    if (split) {
        attn_mfma<<<dim3(512, 2), blk, 0, stream>>>(Qh, Kh, Vt, nullptr, Op, Lm, 16, 1);
        attn_merge<<<dim3(4096), blk, 0, stream>>>(Op, Lm, Yh);
    } else {
        attn_mfma<<<dim3(512, 1), blk, 0, stream>>>(Qh, Kh, Vt, Yh, nullptr, nullptr, 32, 0);
    }
    gemm_out<<<dim3(16, 32), blk, 0, stream>>>(Yh, Woh, out, bo);
}

// Round 15
// 201.713 us; speedup vs baseline: 1.0661x; 1.0661x over previous
//
#include <hip/hip_runtime.h>
#include <math.h>

#define B_DIM 2
#define S_DIM 2048
#define D_DIM 1024
#define H_NUM 16
#define DH    64
#define M_DIM (B_DIM * S_DIM) /* 4096 */

typedef __attribute__((ext_vector_type(8))) short short8;
typedef __attribute__((ext_vector_type(4))) short short4v;
typedef __attribute__((ext_vector_type(4))) float float4v;
typedef __attribute__((ext_vector_type(4))) unsigned short ushort4v;
typedef unsigned short ushort;

static __device__ __forceinline__ ushort f2bf(float f) {
    unsigned u = __float_as_uint(f);
    u += 0x7fffu + ((u >> 16) & 1u);
    return (ushort)(u >> 16);
}

static __device__ __forceinline__ float fexp2(float x) {
#if __has_builtin(__builtin_amdgcn_exp2f)
    return __builtin_amdgcn_exp2f(x);
#else
    return exp2f(x);
#endif
}

// 2 f32 -> 2 bf16 in one u32, lo half = first arg (proven: rounds 3/4
// bit-identical).
static __device__ __forceinline__ unsigned cvtpk_bf16(float lo, float hi) {
    unsigned r;
    asm("v_cvt_pk_bf16_f32 %0, %1, %2" : "=v"(r) : "v"(lo), "v"(hi));
    return r;
}

static __device__ __forceinline__ void gload_lds16(const void* g, void* l) {
    __builtin_amdgcn_global_load_lds(
        (const __attribute__((address_space(1))) void*)g,
        (__attribute__((address_space(3))) void*)l, 16, 0, 0);
}

// ---------------------------------------------------------------------------
// Fused fp32 -> bf16 cast of ALL five tensors in one launch.
// dst layout (contiguous in ws): xh[4M] | wq[1M] | wk[1M] | wv[1M] | wo[1M]
// ---------------------------------------------------------------------------
__global__ __launch_bounds__(256)
void cast_all(const float* __restrict__ x,  const float* __restrict__ wq,
              const float* __restrict__ wk, const float* __restrict__ wv,
              const float* __restrict__ wo, ushort* __restrict__ dst)
{
    const int i = blockIdx.x * 256 + threadIdx.x;   // 0 .. 2M-1 (float4 units)
    const float4* s;
    int off;
    if      (i < 1048576) { s = (const float4*)x;  off = 0;       }
    else if (i < 1310720) { s = (const float4*)wq; off = 1048576; }
    else if (i < 1572864) { s = (const float4*)wk; off = 1310720; }
    else if (i < 1835008) { s = (const float4*)wv; off = 1572864; }
    else                  { s = (const float4*)wo; off = 1835008; }
    const float4 v = s[i - off];
    ushort4v o;
    o[0] = f2bf(v.x); o[1] = f2bf(v.y); o[2] = f2bf(v.z); o[3] = f2bf(v.w);
    ((ushort4v*)dst)[i] = o;
}

// ---------------------------------------------------------------------------
// QKV GEMM, BK=64, double-buffered single-barrier K-loop (R12, verified).
// Granule-XOR LDS swizzle; XCD-aware bijective block swizzle (768=8*96).
// A:[4096,1024] bf16, B:[3072,1024] bf16 row-major.
// n>>10 selects dst: 0->Qh [B,H,S,Dh] (PRE-SCALED by 0.125*log2e),
// 1->Kh [B,H,S,Dh], 2->Vt [B,H,Dh,S]; all bf16.
// ---------------------------------------------------------------------------
__global__ __launch_bounds__(256)
void gemm_bf16(const ushort* __restrict__ A, const ushort* __restrict__ B,
               ushort* __restrict__ Qh, ushort* __restrict__ Kh,
               ushort* __restrict__ Vt)
{
    __shared__ ushort Asm[2][128 * 64];   // [buf][row][k 64], granule-swizzled
    __shared__ ushort Bsm[2][128 * 64];

    const int K = 1024;
    const int NT = 16;                                 // K-tiles
    const int lin = blockIdx.y * 24 + blockIdx.x;      // hardware linear id
    const int swz = (lin & 7) * 96 + (lin >> 3);       // bijective (768=8*96)
    const int n0 = (swz % 24) * 128;
    const int m0 = (swz / 24) * 128;
    const int t    = threadIdx.x;
    const int w    = t >> 6;
    const int lane = t & 63;
    const int n    = lane & 15;
    const int quad = lane >> 4;
    const int wm = w >> 1, wn = w & 1;

    const int l8 = lane >> 3;
    const int sg = (lane & 7) ^ l8;

    const int fswz[2] = { ((0 * 4 + quad) ^ (n & 7)) * 8,
                          ((1 * 4 + quad) ^ (n & 7)) * 8 };

    float4v acc[4][4];
#pragma unroll
    for (int mt = 0; mt < 4; ++mt)
#pragma unroll
        for (int nt = 0; nt < 4; ++nt) acc[mt][nt] = (float4v){0.f, 0.f, 0.f, 0.f};

    // prologue: stage tile 0 into buffer 0
#pragma unroll
    for (int i = 0; i < 4; ++i) {
        gload_lds16(&A[(size_t)(m0 + w * 32 + i * 8 + l8) * K + sg * 8],
                    &Asm[0][(w * 32 + i * 8) * 64]);
        gload_lds16(&B[(size_t)(n0 + w * 32 + i * 8 + l8) * K + sg * 8],
                    &Bsm[0][(w * 32 + i * 8) * 64]);
    }

    for (int kt6 = 0; kt6 < NT; ++kt6) {
        __syncthreads();   // stage(kt6) complete; buf cur^1 free for overwrite
        const int cur = kt6 & 1;
        if (kt6 + 1 < NT) {
            const int kt1 = (kt6 + 1) * 64;
            const int nxt = cur ^ 1;
#pragma unroll
            for (int i = 0; i < 4; ++i) {
                gload_lds16(&A[(size_t)(m0 + w * 32 + i * 8 + l8) * K + kt1 + sg * 8],
                            &Asm[nxt][(w * 32 + i * 8) * 64]);
                gload_lds16(&B[(size_t)(n0 + w * 32 + i * 8 + l8) * K + kt1 + sg * 8],
                            &Bsm[nxt][(w * 32 + i * 8) * 64]);
            }
        }

        short8 af[4][2], bfr[4][2];
#pragma unroll
        for (int mt = 0; mt < 4; ++mt)
#pragma unroll
            for (int kk = 0; kk < 2; ++kk)
                af[mt][kk] = *(const short8*)&Asm[cur][(wm * 64 + mt * 16 + n) * 64 + fswz[kk]];
#pragma unroll
        for (int nt = 0; nt < 4; ++nt)
#pragma unroll
            for (int kk = 0; kk < 2; ++kk)
                bfr[nt][kk] = *(const short8*)&Bsm[cur][(wn * 64 + nt * 16 + n) * 64 + fswz[kk]];

        __builtin_amdgcn_s_setprio(1);
#pragma unroll
        for (int mt = 0; mt < 4; ++mt)
#pragma unroll
            for (int nt = 0; nt < 4; ++nt) {
                acc[mt][nt] = __builtin_amdgcn_mfma_f32_16x16x32_bf16(
                    af[mt][0], bfr[nt][0], acc[mt][nt], 0, 0, 0);
                acc[mt][nt] = __builtin_amdgcn_mfma_f32_16x16x32_bf16(
                    af[mt][1], bfr[nt][1], acc[mt][nt], 0, 0, 0);
            }
        __builtin_amdgcn_s_setprio(0);
    }

    const int wid = n0 >> 10;           // 0=Q 1=K 2=V (constant per block)
    ushort* dstQK = (wid == 0) ? Qh : Kh;
    const float qs = (wid == 0) ? 0.1803368801f : 1.0f;  // 0.125*log2(e)
#pragma unroll
    for (int mt = 0; mt < 4; ++mt) {
        const int m = m0 + wm * 64 + mt * 16 + quad * 4;   // +r
        const int b = m >> 11, s = m & (S_DIM - 1);
#pragma unroll
        for (int nt = 0; nt < 4; ++nt) {
            const int ng = (n0 & 1023) + wn * 64 + nt * 16 + n;
            const int h = ng >> 6, d = ng & 63;
            const int bh = b * H_NUM + h;
            if (wid < 2) {
#pragma unroll
                for (int r = 0; r < 4; ++r)
                    dstQK[(((size_t)bh * S_DIM + s + r) << 6) + d] =
                        f2bf(acc[mt][nt][r] * qs);
            } else {
                ushort4v p;
#pragma unroll
                for (int r = 0; r < 4; ++r) p[r] = f2bf(acc[mt][nt][r]);
                *(ushort4v*)&Vt[(((size_t)bh * DH + d) << 11) + s] = p;
            }
        }
    }
}

// ---------------------------------------------------------------------------
// Out-projection GEMM, 128x64 tile, BK=64, double-buffered (R12, verified).
// Grid (16,32)=512 = 2 blocks/CU; XCD swizzle bijective (512=8*64).
// A=Yh [4096,1024], B=Woh [1024,1024] bf16 row-major.
// fp32 out[m*1024+n] = acc + bias[n].
// ---------------------------------------------------------------------------
__global__ __launch_bounds__(256)
void gemm_out(const ushort* __restrict__ A, const ushort* __restrict__ B,
              float* __restrict__ Of, const float* __restrict__ bias)
{
    __shared__ ushort Asm[2][128 * 64];
    __shared__ ushort Bsm[2][64 * 64];

    const int K = 1024;
    const int NT = 16;
    const int lin = blockIdx.y * 16 + blockIdx.x;
    const int swz = (lin & 7) * 64 + (lin >> 3);       // bijective (512=8*64)
    const int n0 = (swz % 16) * 64;
    const int m0 = (swz / 16) * 128;
    const int t    = threadIdx.x;
    const int w    = t >> 6;
    const int lane = t & 63;
    const int n    = lane & 15;
    const int quad = lane >> 4;
    const int wm = w >> 1, wn = w & 1;

    const int l8 = lane >> 3;
    const int sg = (lane & 7) ^ l8;
    const int fswz[2] = { ((0 * 4 + quad) ^ (n & 7)) * 8,
                          ((1 * 4 + quad) ^ (n & 7)) * 8 };

    float4v acc[4][2];
#pragma unroll
    for (int mt = 0; mt < 4; ++mt)
#pragma unroll
        for (int nt = 0; nt < 2; ++nt) acc[mt][nt] = (float4v){0.f, 0.f, 0.f, 0.f};

    // prologue: stage tile 0 into buffer 0
#pragma unroll
    for (int i = 0; i < 4; ++i)
        gload_lds16(&A[(size_t)(m0 + w * 32 + i * 8 + l8) * K + sg * 8],
                    &Asm[0][(w * 32 + i * 8) * 64]);
#pragma unroll
    for (int i = 0; i < 2; ++i)
        gload_lds16(&B[(size_t)(n0 + w * 16 + i * 8 + l8) * K + sg * 8],
                    &Bsm[0][(w * 16 + i * 8) * 64]);

    for (int kt6 = 0; kt6 < NT; ++kt6) {
        __syncthreads();
        const int cur = kt6 & 1;
        if (kt6 + 1 < NT) {
            const int kt1 = (kt6 + 1) * 64;
            const int nxt = cur ^ 1;
#pragma unroll
            for (int i = 0; i < 4; ++i)
                gload_lds16(&A[(size_t)(m0 + w * 32 + i * 8 + l8) * K + kt1 + sg * 8],
                            &Asm[nxt][(w * 32 + i * 8) * 64]);
#pragma unroll
            for (int i = 0; i < 2; ++i)
                gload_lds16(&B[(size_t)(n0 + w * 16 + i * 8 + l8) * K + kt1 + sg * 8],
                            &Bsm[nxt][(w * 16 + i * 8) * 64]);
        }

        short8 af[4][2], bfr[2][2];
#pragma unroll
        for (int mt = 0; mt < 4; ++mt)
#pragma unroll
            for (int kk = 0; kk < 2; ++kk)
                af[mt][kk] = *(const short8*)&Asm[cur][(wm * 64 + mt * 16 + n) * 64 + fswz[kk]];
#pragma unroll
        for (int nt = 0; nt < 2; ++nt)
#pragma unroll
            for (int kk = 0; kk < 2; ++kk)
                bfr[nt][kk] = *(const short8*)&Bsm[cur][(wn * 32 + nt * 16 + n) * 64 + fswz[kk]];

        __builtin_amdgcn_s_setprio(1);
#pragma unroll
        for (int mt = 0; mt < 4; ++mt)
#pragma unroll
            for (int nt = 0; nt < 2; ++nt) {
                acc[mt][nt] = __builtin_amdgcn_mfma_f32_16x16x32_bf16(
                    af[mt][0], bfr[nt][0], acc[mt][nt], 0, 0, 0);
                acc[mt][nt] = __builtin_amdgcn_mfma_f32_16x16x32_bf16(
                    af[mt][1], bfr[nt][1], acc[mt][nt], 0, 0, 0);
            }
        __builtin_amdgcn_s_setprio(0);
    }

#pragma unroll
    for (int mt = 0; mt < 4; ++mt) {
        const int m = m0 + wm * 64 + mt * 16 + quad * 4;
#pragma unroll
        for (int nt = 0; nt < 2; ++nt) {
            const int ng = n0 + wn * 32 + nt * 16 + n;
            const float bv = bias[ng];
#pragma unroll
            for (int r = 0; r < 4; ++r)
                Of[(size_t)(m + r) * D_DIM + ng] = acc[mt][nt][r] + bv;
        }
    }
}

// ---------------------------------------------------------------------------
// MFMA flash attention: R12 single-pass kernel with __launch_bounds__(256,3).
// R13 proved occupancy is REGISTER-capped, not grid-capped: doubling the
// grid (split-KV) left OccupancyPercent at 18% -- the unified VGPR+AGPR
// total (~100 arch + ~72 acc) exceeds 170/wave, capping at 2 waves/SIMD.
// Forcing min 3 waves/EU makes the allocator fit <=170 total regs/wave
// (12 waves/CU, +50% TLP for this latency-bound kernel).
// 32 q-rows/wave, 4-wave blocks, grid 512. Swapped QK^T, fully LOCAL P->PV
// handoff via the k-slot->key remap slot q*8+e <-> key 32kc+16(e>>2)+4q+(e&3).
// Defer-max (THR=8, base-2); Q pre-scaled by 0.125*log2e; cvt_pk packing.
// ---------------------------------------------------------------------------
__global__ __launch_bounds__(256, 3)
void attn_mfma(const ushort* __restrict__ Qh, const ushort* __restrict__ Kh,
               const ushort* __restrict__ Vt, ushort* __restrict__ Yh)
{
    __shared__ ushort Ksm[2][64 * 64];   // [buf][key 64][d 64] granule-swizzled
    __shared__ ushort Vsm[2][64 * 64];   // [buf][d 64][key 64] granule-swizzled

    const int w    = threadIdx.x >> 6;
    const int lane = threadIdx.x & 63;
    const int n    = lane & 15;
    const int quad = lane >> 4;

    const int wave_id = blockIdx.x * 4 + w;
    const int bh    = wave_id >> 6;          // all 4 waves of a block: same bh
    const int qbase = (wave_id & 63) * 32;
    const int b     = bh >> 4;
    const int h     = bh & (H_NUM - 1);

    const ushort* Qb = Qh + (((size_t)bh * S_DIM) << 6);
    const ushort* Kb = Kh + (((size_t)bh * S_DIM) << 6);
    const ushort* Vb = Vt + (((size_t)bh * DH) << 11);

    const int l8 = lane >> 3;
    const int sg = (lane & 7) ^ l8;

    short8 qa[2][2];   // B-frag: lane holds Q[q = mt*16+n][d = kc*32+quad*8 ..]
#pragma unroll
    for (int mt = 0; mt < 2; ++mt)
#pragma unroll
        for (int kc = 0; kc < 2; ++kc)
            qa[mt][kc] = *(const short8*)&Qb[((size_t)(qbase + mt * 16 + n) << 6) + kc * 32 + quad * 8];

    float4v O[2][4];           // O[mt][nt][r]: q = mt*16+quad*4+r, d = nt*16+n
    float   mrow[2], lrow[2];  // per-lane: q = mt*16 + n (uniform over quads)
#pragma unroll
    for (int mt = 0; mt < 2; ++mt) {
#pragma unroll
        for (int nt = 0; nt < 4; ++nt) O[mt][nt] = (float4v){0.f, 0.f, 0.f, 0.f};
        mrow[mt] = -1e30f; lrow[mt] = 0.f;
    }

    const int fswz[2] = { ((0 * 4 + quad) ^ (n & 7)) * 8,
                          ((1 * 4 + quad) ^ (n & 7)) * 8 };
    const int h4 = (quad & 1) * 4;
    const int q2 = quad >> 1;
    int vswz[2][2];
#pragma unroll
    for (int kc = 0; kc < 2; ++kc)
#pragma unroll
        for (int cc = 0; cc < 2; ++cc)
            vswz[kc][cc] = (((4 * kc + 2 * cc + q2) ^ (n & 7)) << 3) + h4;

    // prologue: stage tile 0 into buffer 0
#pragma unroll
    for (int i = 0; i < 2; ++i) {
        gload_lds16(&Kb[(size_t)(w * 16 + i * 8 + l8) * 64 + sg * 8],
                    &Ksm[0][(w * 16 + i * 8) * 64]);
        gload_lds16(&Vb[(size_t)(w * 16 + i * 8 + l8) * 2048 + sg * 8],
                    &Vsm[0][(w * 16 + i * 8) * 64]);
    }

    for (int kb = 0; kb < S_DIM / 64; ++kb) {
        __syncthreads();   // stage(kb) complete; buf cur^1 free for overwrite
        const int cur = kb & 1;
        if (kb + 1 < S_DIM / 64) {
            const int key1 = (kb + 1) * 64;
            const int nxt  = cur ^ 1;
#pragma unroll
            for (int i = 0; i < 2; ++i) {
                gload_lds16(&Kb[(size_t)(key1 + w * 16 + i * 8 + l8) * 64 + sg * 8],
                            &Ksm[nxt][(w * 16 + i * 8) * 64]);
                gload_lds16(&Vb[(size_t)(w * 16 + i * 8 + l8) * 2048 + key1 + sg * 8],
                            &Vsm[nxt][(w * 16 + i * 8) * 64]);
            }
        }

        // A-frag: lane holds K[key = ct*16+n][d = kc*32+quad*8 ..]
        short8 kf[4][2];
#pragma unroll
        for (int ct = 0; ct < 4; ++ct)
#pragma unroll
            for (int kc = 0; kc < 2; ++kc)
                kf[ct][kc] = *(const short8*)&Ksm[cur][(ct * 16 + n) * 64 + fswz[kc]];

        // S^T[key][q]: s[mt][ct][r] = S[q = mt*16+n][key = ct*16+quad*4+r]
        float4v s[2][4];
        __builtin_amdgcn_s_setprio(1);
#pragma unroll
        for (int mt = 0; mt < 2; ++mt)
#pragma unroll
            for (int ct = 0; ct < 4; ++ct) {
                float4v a = (float4v){0.f, 0.f, 0.f, 0.f};
                a = __builtin_amdgcn_mfma_f32_16x16x32_bf16(kf[ct][0], qa[mt][0], a, 0, 0, 0);
                a = __builtin_amdgcn_mfma_f32_16x16x32_bf16(kf[ct][1], qa[mt][1], a, 0, 0, 0);
                s[mt][ct] = a;
            }
        __builtin_amdgcn_s_setprio(0);

        // B-frag under remap: slot q*8+e holds V[key = 32kc+16(e>>2)+4q+(e&3)]
        short8 vf[4][2];
#pragma unroll
        for (int nt = 0; nt < 4; ++nt) {
            const int rb = (nt * 16 + n) * 64;
#pragma unroll
            for (int kc = 0; kc < 2; ++kc) {
                const short4v g0 = *(const short4v*)&Vsm[cur][rb + vswz[kc][0]];
                const short4v g1 = *(const short4v*)&Vsm[cur][rb + vswz[kc][1]];
                vf[nt][kc] = __builtin_shufflevector(g0, g1, 0, 1, 2, 3, 4, 5, 6, 7);
            }
        }

#pragma unroll
        for (int mt = 0; mt < 2; ++mt) {
            // tile max for q = mt*16+n (my 16 keys, then across quads)
            float lm = s[mt][0][0];
#pragma unroll
            for (int ct = 0; ct < 4; ++ct)
#pragma unroll
                for (int r = 0; r < 4; ++r)
                    lm = fmaxf(lm, s[mt][ct][r]);
            lm = fmaxf(lm, __shfl_xor(lm, 16, 64));
            lm = fmaxf(lm, __shfl_xor(lm, 32, 64));

            const bool ev = lm > mrow[mt] + 8.0f;   // defer-max threshold
            if (__any(ev)) {
                const float mnew  = ev ? lm : mrow[mt];
                const float alpha = fexp2(mrow[mt] - mnew);  // 1.0 when !ev
                mrow[mt] = mnew;
                lrow[mt] *= alpha;
                const int ai = __float_as_int(alpha);
                float av[4];
#pragma unroll
                for (int r = 0; r < 4; ++r)
                    av[r] = __int_as_float(
                        __builtin_amdgcn_ds_bpermute(4 * (quad * 4 + r), ai));
#pragma unroll
                for (int nt = 0; nt < 4; ++nt)
#pragma unroll
                    for (int r = 0; r < 4; ++r) O[mt][nt][r] *= av[r];
            }

            // P = 2^(s - m); l as local partial (reduced once at the end)
            float pv[4][4];
            float lsum = 0.f;
#pragma unroll
            for (int ct = 0; ct < 4; ++ct)
#pragma unroll
                for (int r = 0; r < 4; ++r) {
                    const float p = fexp2(s[mt][ct][r] - mrow[mt]);
                    pv[ct][r] = p;
                    lsum += p;
                }
            lrow[mt] += lsum;

            // PV A-frag is PURELY LOCAL under the remap:
            // element e of pk[kc] = pv[2kc + (e>>2)][e&3]; cvt_pk = 1 instr.
            union { unsigned u[4]; short8 s8; } pk[2];
#pragma unroll
            for (int kc = 0; kc < 2; ++kc) {
                pk[kc].u[0] = cvtpk_bf16(pv[2 * kc][0],     pv[2 * kc][1]);
                pk[kc].u[1] = cvtpk_bf16(pv[2 * kc][2],     pv[2 * kc][3]);
                pk[kc].u[2] = cvtpk_bf16(pv[2 * kc + 1][0], pv[2 * kc + 1][1]);
                pk[kc].u[3] = cvtpk_bf16(pv[2 * kc + 1][2], pv[2 * kc + 1][3]);
            }

            __builtin_amdgcn_s_setprio(1);
#pragma unroll
            for (int nt = 0; nt < 4; ++nt) {
                O[mt][nt] = __builtin_amdgcn_mfma_f32_16x16x32_bf16(pk[0].s8, vf[nt][0], O[mt][nt], 0, 0, 0);
                O[mt][nt] = __builtin_amdgcn_mfma_f32_16x16x32_bf16(pk[1].s8, vf[nt][1], O[mt][nt], 0, 0, 0);
            }
            __builtin_amdgcn_s_setprio(0);
        }
    }

#pragma unroll
    for (int mt = 0; mt < 2; ++mt) {
        float ls = lrow[mt];
        ls += __shfl_xor(ls, 16, 64);
        ls += __shfl_xor(ls, 32, 64);
        const float linv = 1.f / ls;            // at lane: q = mt*16 + n
        const int  li = __float_as_int(linv);
        float lv[4];
#pragma unroll
        for (int r = 0; r < 4; ++r)
            lv[r] = __int_as_float(
                __builtin_amdgcn_ds_bpermute(4 * (quad * 4 + r), li));
#pragma unroll
        for (int nt = 0; nt < 4; ++nt)
#pragma unroll
            for (int r = 0; r < 4; ++r) {
                const int q = qbase + mt * 16 + quad * 4 + r;
                Yh[((size_t)(b * S_DIM + q) << 10) + h * DH + nt * 16 + n] =
                    f2bf(O[mt][nt][r] * lv[r]);
            }
    }
}

// ---------------------------------------------------------------------------
extern "C" void kernel_launch(void* const* d_in, const int* in_sizes, int n_in,
                              void* d_out, int out_size, void* d_ws, size_t ws_size,
                              hipStream_t stream)
{
    const float* x  = (const float*)d_in[0];
    const float* wq = (const float*)d_in[1];
    const float* wk = (const float*)d_in[2];
    const float* wv = (const float*)d_in[3];
    const float* wo = (const float*)d_in[4];
    const float* bo = (const float*)d_in[5];
    float* out = (float*)d_out;

    const size_t MD = (size_t)M_DIM * D_DIM;      // 4M elements
    const size_t WD = (size_t)D_DIM * D_DIM;      // 1M elements
    ushort* xh  = (ushort*)d_ws;      // 8 MB  [M,K] bf16
    ushort* Wh  = xh + MD;            // 6 MB  [3072,1024] bf16 (wq|wk|wv)
    ushort* Woh = Wh + 3 * WD;        // 2 MB  [1024,1024] bf16
    ushort* Qh  = Woh + WD;           // 8 MB  [B,H,S,Dh] bf16 (pre-scaled)
    ushort* Kh  = Qh + MD;            // 8 MB  [B,H,S,Dh] bf16
    ushort* Vt  = Kh + MD;            // 8 MB  [B,H,Dh,S] bf16
    ushort* Yh  = Vt + MD;            // 8 MB  [M,D] bf16
    if (ws_size < 48u * 1024u * 1024u) return;

    dim3 blk(256);
    cast_all<<<dim3(8192), blk, 0, stream>>>(x, wq, wk, wv, wo, xh);

    gemm_bf16<<<dim3(24, 32), blk, 0, stream>>>(xh, Wh, Qh, Kh, Vt);
    attn_mfma<<<dim3(512), blk, 0, stream>>>(Qh, Kh, Vt, Yh);
    gemm_out<<<dim3(16, 32), blk, 0, stream>>>(Yh, Woh, out, bo);
}